// Round 20
// baseline (123.170 us; speedup 1.0000x reference)
//
#include <hip/hip_runtime.h>
#include <math.h>

#define NBINS 80
#define NVERT 128
#define NRH 5
#define NDEG 6           // Taylor terms d=0..5; remainder ~1e-5 (<< f16 eps)

#define PSTR 136         // halves per P/M row; cols 0..127 data, 128..135 pad
#define VSTR 32          // halves per VT row
#define DSTR 80          // halves per desc row

#define OFF_VT 6800      // P/M: 25*136*2 = 6800 B at [0,6800)
#define VTSZ   6144      // per-wave VT copy: 96*32*2
#define OFF_GM 19088     // gm f16 x 128 = 256 B
#define OFF_CNT 19344    // 2 ints
#define SLICE  19360     // per-sample slice; desc overlays the VT region [6800,17040)

#define NSET_C 48        // C-matrix frag sets: 16 nt x 3 ks
#define NSET_W 60        // W frag sets: 4 i x 5 tiles x 3 ks
#define WS_BYTES ((NSET_C + NSET_W) * 64 * 8 * 2)

typedef _Float16 half8 __attribute__((ext_vector_type(8)));
typedef float f32x4 __attribute__((ext_vector_type(4)));

// ---- prep: constant C-matrix frags + W frags in d_ws (unchanged, verified) ----
__global__ __launch_bounds__(64) void prep_frags(const float* __restrict__ Wc,
                                                 const float* __restrict__ sig_th,
                                                 _Float16* __restrict__ ws) {
    const int blk  = blockIdx.x;
    const int lane = threadIdx.x;
    constexpr float TWO_PI = 6.28318530717958647692f;
    constexpr float DLT    = TWO_PI / 16.0f;
    constexpr float LN2    = 0.69314718055994530942f;
    half8 h;
    if (blk < NSET_C) {
        constexpr float LOG2E = 1.44269504088896340736f;
        constexpr float EPSF  = 1e-5f;
        const float st = sig_th[0];
        const float Kt = -LOG2E / (st * st + EPSF);
        const int ks = blk % 3;
        const int nt = blk / 3;
        const int t  = lane & 15;
        const int q  = lane >> 4;
        #pragma unroll
        for (int j = 0; j < 8; ++j) {
            const int k = ks * 32 + q * 8 + j;     // 0..95
            const int a = k / NDEG;
            const int d = k % NDEG;
            const int m = ((a + nt) & 15) - t;
            const float s = fmaf((float)m, DLT, 0.5f * DLT);
            const float z = 2.0f * LN2 * Kt * s * (0.5f * DLT);
            float val = exp2f(Kt * s * s);
            for (int dd = 1; dd <= d; ++dd) val *= z / (float)dd;
            h[j] = (_Float16)val;
        }
    } else {
        const int e    = blk - NSET_C;
        const int ks   = e % 3;
        const int tile = (e / 3) % 5;
        const int i    = e / 15;
        const int cc   = tile * 16 + (lane & 15);
        const int bb0  = ks * 32 + (lane >> 4) * 8;
        #pragma unroll
        for (int j = 0; j < 8; ++j) {
            const int bb = bb0 + j;
            h[j] = (_Float16)((bb < NBINS) ? Wc[i * NBINS * NBINS + bb * NBINS + cc] : 0.0f);
        }
    }
    *(half8*)(ws + ((size_t)blk * 64 + lane) * 8) = h;
}

// 256-thread block = TWO independent samples, each with R16's verified 2-wave
// split. R19 deltas: desc lives in the (dead-after-chain1) VT region, so the
// A-frag/desc race barrier is gone (4 barriers); chain2's first-group ws
// B-frags are prefetched before chain1 so their L2 latency hides under it.
template <int USEWS>
__global__ __launch_bounds__(256) void masif_geo_conv(
    const float* __restrict__ rho_c,
    const float* __restrict__ th_c,
    const float* __restrict__ feat_g,
    const float* __restrict__ mask_g,
    const float* __restrict__ mu_rho,
    const float* __restrict__ sig_rho,
    const float* __restrict__ mu_th,
    const float* __restrict__ sig_th,
    const float* __restrict__ Wc,
    const float* __restrict__ bcv,
    const _Float16* __restrict__ ws,
    const int nsamp,
    float* __restrict__ out)
{
    const int tid  = threadIdx.x;
    const int wave = tid >> 6;
    const int lane = tid & 63;
    const int sw   = wave & 1;    // R16 wave role within sample
    const int sh   = wave >> 1;   // which sample of the pair
    int n = blockIdx.x * 2 + sh;
    if (n >= nsamp) n = nsamp - 1;   // duplicate compute, identical writes (benign)

    const int t  = lane & 15;
    const int kq = lane >> 4;

    __shared__ __align__(16) char s_raw[2 * SLICE];
    char* slice = s_raw + sh * SLICE;
    _Float16* s_PM  = (_Float16*)(slice);                      // P / M (persistent)
    _Float16* s_vtw = (_Float16*)(slice + OFF_VT + sw * VTSZ); // own VT copy
    _Float16* s_gm  = (_Float16*)(slice + OFF_GM);
    int*      s_cnt = (int*)(slice + OFF_CNT);
    _Float16* s_d   = (_Float16*)(slice + OFF_VT);             // desc: VT region (dead after chain1)

    constexpr float LOG2E   = 1.44269504088896340736f;
    constexpr float TWO_PI  = 6.28318530717958647692f;
    constexpr float DLT     = TWO_PI / 16.0f;
    constexpr float INV_DLT = 16.0f / TWO_PI;
    constexpr float EPSF    = 1e-5f;

    const float st = sig_th[0];
    const float Kt = -LOG2E / (st * st + EPSF);
    const float sr = sig_rho[0];
    const float Kr = -LOG2E / (sr * sr + EPSF);
    float mr[NRH];
    #pragma unroll
    for (int r = 0; r < NRH; ++r) mr[r] = mu_rho[r * 16];

    // ---- zero P incl. pads (per-slice 425 int4, by that slice's 2 waves) ----
    #pragma unroll
    for (int x = 0; x < 4; ++x) {
        const int idx = x * 128 + sw * 64 + lane;
        if (idx < 425) ((int4*)s_PM)[idx] = make_int4(0, 0, 0, 0);
    }

    // ---- compaction: wave sw handles verts 64sw..64sw+63 of sample n ----
    const int v = sw * 64 + lane;
    const float  m   = mask_g[n * NVERT + v];
    const float  th0 = th_c[n * NVERT + v];
    const float  rho = rho_c[n * NVERT + v];
    const float4 f4  = *(const float4*)&feat_g[(n * NVERT + v) * 4];
    const bool act = (m != 0.0f);
    const unsigned long long bal = __ballot(act);
    if (lane == 0) s_cnt[sw] = (int)__popcll(bal);
    __syncthreads();                                        // [1] counts + P zero
    const int base = sw ? s_cnt[0] : 0;
    const int nc   = s_cnt[0] + s_cnt[1];
    if (act) {
        const int pos = base + (int)__popcll(bal & ((1ull << lane) - 1ull));
        int aa = (int)floorf(th0 * INV_DLT);
        aa = aa > 15 ? 15 : (aa < 0 ? 0 : aa);
        const float rvp = th0 - (float)aa * DLT - 0.5f * DLT;   // [-DLT/2, DLT/2)
        float R[NRH];
        #pragma unroll
        for (int r = 0; r < NRH; ++r) {
            const float dr = rho - mr[r];
            R[r] = m * exp2f(Kr * dr * dr);
        }
        const float fv[4] = {f4.x, f4.y, f4.z, f4.w};
        #pragma unroll
        for (int f = 0; f < 4; ++f) {
            #pragma unroll
            for (int r = 0; r < 4; ++r)
                s_PM[(f * 4 + r) * PSTR + pos] = (_Float16)(fv[f] * R[r]);
            s_PM[(16 + f) * PSTR + pos] = (_Float16)(fv[f] * R[4]);
        }
        #pragma unroll
        for (int r = 0; r < NRH; ++r)
            s_PM[(20 + r) * PSTR + pos] = (_Float16)R[r];
        s_PM[(pos >> 3) * PSTR + 128 + (pos & 7)] = (_Float16)(rvp * (2.0f * INV_DLT));
        ((char*)s_PM)[(16 + (pos >> 4)) * 2 * PSTR + 256 + (pos & 15)] = (char)aa;
        s_gm[pos] = (_Float16)exp2f(Kt * rvp * rvp);
    }
    __syncthreads();                                        // [2] P/gm/tails complete

    // ---- prefetch chain2 group-0 ws B-frags (latency hides under chain1) ----
    const half8* wsv = (const half8*)ws;
    half8 Bp0[4], Bp1[4], Bp2[4];
    if (USEWS) {
        #pragma unroll
        for (int j = 0; j < 4; ++j) {
            const int nt = (sw * 2) * 4 + j;
            Bp0[j] = wsv[(size_t)((nt * 3 + 0) * 64 + lane)];
            Bp1[j] = wsv[(size_t)((nt * 3 + 1) * 64 + lane)];
            Bp2[j] = wsv[(size_t)((nt * 3 + 2) * 64 + lane)];
        }
    }

    // ---- chain 1 (R16-verified): wave sw -> M tile sw, own VT copy ----
    f32x4 M[NDEG];
    #pragma unroll
    for (int ct = 0; ct < NDEG; ++ct) M[ct] = (f32x4){0.f, 0.f, 0.f, 0.f};
    const int arow = sw ? (16 + t) : t;
    const int nch = (nc + 31) >> 5;
    #pragma unroll 1
    for (int ch = 0; ch < nch; ++ch) {
        #pragma unroll
        for (int x = 0; x < 6; ++x)
            ((int4*)s_vtw)[x * 64 + lane] = make_int4(0, 0, 0, 0);
        {
            const int cl = lane >> 1;
            const int cg = ch * 32 + cl;
            if (cg < nc) {
                const float u = (float)s_PM[(cg >> 3) * PSTR + 128 + (cg & 7)];
                const float g = (float)s_gm[cg];
                const int   a = (int)((char*)s_PM)[(16 + (cg >> 4)) * 2 * PSTR + 256 + (cg & 15)];
                const int  dh = (lane & 1) * 3;
                float p0, p1, p2;
                if (dh == 0) { p0 = 1.0f; p1 = u; p2 = u * u; }
                else { const float u2 = u * u; p0 = u2 * u; p1 = u2 * u2; p2 = p0 * u2; }
                const int bi = (a * NDEG + dh) * VSTR + cl;
                s_vtw[bi]            = (_Float16)(g * p0);
                s_vtw[bi + VSTR]     = (_Float16)(g * p1);
                s_vtw[bi + 2 * VSTR] = (_Float16)(g * p2);
            }
        }
        const half8 a = *(const half8*)(s_PM + arow * PSTR + ch * 32 + kq * 8);
        #pragma unroll
        for (int ct = 0; ct < NDEG; ++ct) {
            const half8 b = *(const half8*)(s_vtw + (ct * 16 + t) * VSTR + kq * 8);
            M[ct] = __builtin_amdgcn_mfma_f32_16x16x32_f16(a, b, M[ct], 0, 0, 0);
        }
    }

    // ---- M -> LDS f16 A-layout. D: col=t, row=kq*4+reg ----
    #pragma unroll
    for (int ct = 0; ct < NDEG; ++ct) {
        const int md = ct * 16 + t;
        #pragma unroll
        for (int reg = 0; reg < 4; ++reg) {
            const int lr = kq * 4 + reg;
            if (sw == 0)
                s_PM[lr * PSTR + md] = (_Float16)M[ct][reg];
            else if (lr < 9)
                s_PM[(16 + lr) * PSTR + md] = (_Float16)M[ct][reg];
        }
    }
    __syncthreads();                                        // [3] M complete (VT now dead)

    // ---- chain2 A-frags -> regs (both tiles); desc goes to VT region, so
    //      no barrier needed between these reads and desc writes ----
    half8 A0[3], A1[3];
    #pragma unroll
    for (int ks = 0; ks < 3; ++ks) {
        A0[ks] = *(const half8*)(s_PM + t * PSTR + ks * 32 + kq * 8);
        A1[ks] = *(const half8*)(s_PM + (16 + t) * PSTR + ks * 32 + kq * 8);
    }

    // ---- chain 2: wave sw -> nt-groups 2sw, 2sw+1; fused epilogue.
    //      gg fully unrolled: group 0 uses prefetched B-frags. ----
    #pragma unroll
    for (int gg = 0; gg < 2; ++gg) {
        const int g = sw * 2 + gg;
        f32x4 C0g[4], C1g[4];
        #pragma unroll
        for (int j = 0; j < 4; ++j) {
            C0g[j] = (f32x4){0.f, 0.f, 0.f, 0.f};
            C1g[j] = (f32x4){0.f, 0.f, 0.f, 0.f};
        }
        #pragma unroll
        for (int j = 0; j < 4; ++j) {
            const int nt = g * 4 + j;
            half8 b0, b1, b2;
            if (USEWS) {
                if (gg == 0) {
                    b0 = Bp0[j]; b1 = Bp1[j]; b2 = Bp2[j];
                } else {
                    b0 = wsv[(size_t)((nt * 3 + 0) * 64 + lane)];
                    b1 = wsv[(size_t)((nt * 3 + 1) * 64 + lane)];
                    b2 = wsv[(size_t)((nt * 3 + 2) * 64 + lane)];
                }
            } else {
                #pragma unroll
                for (int ks = 0; ks < 3; ++ks) {
                    half8 bb;
                    #pragma unroll
                    for (int jj = 0; jj < 8; ++jj) {
                        const int k = ks * 32 + kq * 8 + jj;
                        const int a = k / NDEG, d = k % NDEG;
                        const int mm = ((a + nt) & 15) - t;
                        const float s = fmaf((float)mm, DLT, 0.5f * DLT);
                        const float z = 2.0f * 0.69314718055994530942f * Kt * s * (0.5f * DLT);
                        float val = exp2f(Kt * s * s);
                        for (int dd = 1; dd <= d; ++dd) val *= z / (float)dd;
                        bb[jj] = (_Float16)val;
                    }
                    if (ks == 0) b0 = bb; else if (ks == 1) b1 = bb; else b2 = bb;
                }
            }
            C0g[j] = __builtin_amdgcn_mfma_f32_16x16x32_f16(A0[0], b0, C0g[j], 0, 0, 0);
            C1g[j] = __builtin_amdgcn_mfma_f32_16x16x32_f16(A1[0], b0, C1g[j], 0, 0, 0);
            C0g[j] = __builtin_amdgcn_mfma_f32_16x16x32_f16(A0[1], b1, C0g[j], 0, 0, 0);
            C1g[j] = __builtin_amdgcn_mfma_f32_16x16x32_f16(A1[1], b1, C1g[j], 0, 0, 0);
            C0g[j] = __builtin_amdgcn_mfma_f32_16x16x32_f16(A0[2], b2, C0g[j], 0, 0, 0);
            C1g[j] = __builtin_amdgcn_mfma_f32_16x16x32_f16(A1[2], b2, C1g[j], 0, 0, 0);
        }
        // fused epilogue (R5-verified): desc = num/(den+eps) -> s_d[i][k][bb]
        #pragma unroll
        for (int j = 0; j < 4; ++j) {
            const int nt = g * 4 + j;
            float den[5], inv[5];
            #pragma unroll
            for (int r = 0; r < 4; ++r) den[r] = __shfl(C1g[j][r], 16 + t);
            den[4] = __shfl(C1g[j][0], 32 + t);
            #pragma unroll
            for (int r = 0; r < NRH; ++r) {
                const float x = den[r] + EPSF;
                float vv = __builtin_amdgcn_rcpf(x);
                inv[r] = vv * (2.0f - x * vv);
            }
            #pragma unroll
            for (int reg = 0; reg < 4; ++reg)
                s_d[kq * 1280 + nt * DSTR + reg * 16 + t] =
                    (_Float16)(C0g[j][reg] * inv[reg]);
            if (kq == 0) {
                #pragma unroll
                for (int reg = 0; reg < 4; ++reg)
                    s_d[reg * 1280 + nt * DSTR + 64 + t] =
                        (_Float16)(C1g[j][reg] * inv[4]);
            }
        }
    }
    __syncthreads();                                        // [4] desc complete

    // ---- phase 2: wave sw -> features 2sw, 2sw+1 ----
    #pragma unroll 1
    for (int ii = 0; ii < 2; ++ii) {
        const int i = sw * 2 + ii;
        f32x4 Cc[5];
        #pragma unroll
        for (int tl = 0; tl < 5; ++tl) Cc[tl] = (f32x4){0.f, 0.f, 0.f, 0.f};
        #pragma unroll
        for (int ks = 0; ks < 3; ++ks) {
            const half8 a = *(const half8*)(s_d + i * 1280 + t * DSTR + ks * 32 + kq * 8);
            #pragma unroll
            for (int tl = 0; tl < 5; ++tl) {
                half8 b;
                if (USEWS) {
                    b = wsv[(size_t)((NSET_C + (i * 5 + tl) * 3 + ks) * 64 + lane)];
                } else {
                    const int cc  = tl * 16 + t;
                    const int bb0 = ks * 32 + kq * 8;
                    #pragma unroll
                    for (int j = 0; j < 8; ++j) {
                        const int bb = bb0 + j;
                        b[j] = (_Float16)((bb < NBINS) ? Wc[i * NBINS * NBINS + bb * NBINS + cc] : 0.0f);
                    }
                }
                Cc[tl] = __builtin_amdgcn_mfma_f32_16x16x32_f16(a, b, Cc[tl], 0, 0, 0);
            }
        }
        #pragma unroll
        for (int tl = 0; tl < 5; ++tl) {
            float mx = fmaxf(fmaxf(Cc[tl][0], Cc[tl][1]), fmaxf(Cc[tl][2], Cc[tl][3]));
            mx = fmaxf(mx, __shfl_xor(mx, 16));
            mx = fmaxf(mx, __shfl_xor(mx, 32));
            if (lane < 16) {
                const int cc = tl * 16 + lane;
                out[(size_t)n * 320 + i * NBINS + cc] =
                    fmaxf(mx + bcv[i * NBINS + cc], 0.0f);
            }
        }
    }
}

extern "C" void kernel_launch(void* const* d_in, const int* in_sizes, int n_in,
                              void* d_out, int out_size, void* d_ws, size_t ws_size,
                              hipStream_t stream) {
    const float* rho   = (const float*)d_in[0];
    const float* theta = (const float*)d_in[1];
    const float* feat  = (const float*)d_in[2];
    const float* mask  = (const float*)d_in[3];
    const float* mu_r  = (const float*)d_in[4];
    const float* sg_r  = (const float*)d_in[5];
    const float* mu_t  = (const float*)d_in[6];
    const float* sg_t  = (const float*)d_in[7];
    const float* W     = (const float*)d_in[8];
    const float* bconv = (const float*)d_in[9];
    float* outp = (float*)d_out;

    const int nsamp = in_sizes[0] / NVERT;
    const int useWs = (ws_size >= (size_t)WS_BYTES) ? 1 : 0;
    _Float16* wsh = (_Float16*)d_ws;
    const int nblk = (nsamp + 1) / 2;

    if (useWs) {
        prep_frags<<<NSET_C + NSET_W, 64, 0, stream>>>(W, sg_t, wsh);
        masif_geo_conv<1><<<nblk, 256, 0, stream>>>(
            rho, theta, feat, mask, mu_r, sg_r, mu_t, sg_t, W, bconv,
            wsh, nsamp, outp);
    } else {
        masif_geo_conv<0><<<nblk, 256, 0, stream>>>(
            rho, theta, feat, mask, mu_r, sg_r, mu_t, sg_t, W, bconv,
            wsh, nsamp, outp);
    }
}

// Round 21
// 119.791 us; speedup vs baseline: 1.0282x; 1.0282x over previous
//
#include <hip/hip_runtime.h>
#include <math.h>

#define NBINS 80
#define NVERT 128
#define NRH 5
#define NDEG 6           // Taylor terms d=0..5; remainder ~1e-5 (<< f16 eps)

#define PSTR 136         // halves per P/M row; cols 0..127 data, 128..135 pad
#define VSTR 32          // halves per VT row
#define DSTR 80          // halves per desc row

#define OFF_VT 6800      // P/M: 25*136*2 = 6800 B at [0,6800)
#define VTSZ   6144      // per-wave VT copy: 96*32*2
#define OFF_GM 19088     // gm f16 x 128 = 256 B
#define OFF_CNT 19344    // 2 ints
#define SLICE  19360     // per-sample slice; desc overlays the VT region [6800,17040)

#define NSET_C 48        // C-matrix frag sets: 16 nt x 3 ks
#define NSET_W 60        // W frag sets: 4 i x 5 tiles x 3 ks
#define WS_BYTES ((NSET_C + NSET_W) * 64 * 8 * 2)

typedef _Float16 half8 __attribute__((ext_vector_type(8)));
typedef float f32x4 __attribute__((ext_vector_type(4)));

// ---- prep: constant C-matrix frags + W frags in d_ws (unchanged, verified) ----
__global__ __launch_bounds__(64) void prep_frags(const float* __restrict__ Wc,
                                                 const float* __restrict__ sig_th,
                                                 _Float16* __restrict__ ws) {
    const int blk  = blockIdx.x;
    const int lane = threadIdx.x;
    constexpr float TWO_PI = 6.28318530717958647692f;
    constexpr float DLT    = TWO_PI / 16.0f;
    constexpr float LN2    = 0.69314718055994530942f;
    half8 h;
    if (blk < NSET_C) {
        constexpr float LOG2E = 1.44269504088896340736f;
        constexpr float EPSF  = 1e-5f;
        const float st = sig_th[0];
        const float Kt = -LOG2E / (st * st + EPSF);
        const int ks = blk % 3;
        const int nt = blk / 3;
        const int t  = lane & 15;
        const int q  = lane >> 4;
        #pragma unroll
        for (int j = 0; j < 8; ++j) {
            const int k = ks * 32 + q * 8 + j;     // 0..95
            const int a = k / NDEG;
            const int d = k % NDEG;
            const int m = ((a + nt) & 15) - t;
            const float s = fmaf((float)m, DLT, 0.5f * DLT);
            const float z = 2.0f * LN2 * Kt * s * (0.5f * DLT);
            float val = exp2f(Kt * s * s);
            for (int dd = 1; dd <= d; ++dd) val *= z / (float)dd;
            h[j] = (_Float16)val;
        }
    } else {
        const int e    = blk - NSET_C;
        const int ks   = e % 3;
        const int tile = (e / 3) % 5;
        const int i    = e / 15;
        const int cc   = tile * 16 + (lane & 15);
        const int bb0  = ks * 32 + (lane >> 4) * 8;
        #pragma unroll
        for (int j = 0; j < 8; ++j) {
            const int bb = bb0 + j;
            h[j] = (_Float16)((bb < NBINS) ? Wc[i * NBINS * NBINS + bb * NBINS + cc] : 0.0f);
        }
    }
    *(half8*)(ws + ((size_t)blk * 64 + lane) * 8) = h;
}

// 256-thread block = TWO independent samples, each with R16's verified 2-wave
// split (R18 structure). R20 delta vs R18: desc lives in the dead-after-chain1
// VT region, removing the A-frag/desc race barrier (4 barriers total).
// R19 lesson: NO register-resident prefetch across chain1 (VGPR 56->68 cost
// more residency than the latency hide gained).
template <int USEWS>
__global__ __launch_bounds__(256) void masif_geo_conv(
    const float* __restrict__ rho_c,
    const float* __restrict__ th_c,
    const float* __restrict__ feat_g,
    const float* __restrict__ mask_g,
    const float* __restrict__ mu_rho,
    const float* __restrict__ sig_rho,
    const float* __restrict__ mu_th,
    const float* __restrict__ sig_th,
    const float* __restrict__ Wc,
    const float* __restrict__ bcv,
    const _Float16* __restrict__ ws,
    const int nsamp,
    float* __restrict__ out)
{
    const int tid  = threadIdx.x;
    const int wave = tid >> 6;
    const int lane = tid & 63;
    const int sw   = wave & 1;    // R16 wave role within sample
    const int sh   = wave >> 1;   // which sample of the pair
    int n = blockIdx.x * 2 + sh;
    if (n >= nsamp) n = nsamp - 1;   // duplicate compute, identical writes (benign)

    const int t  = lane & 15;
    const int kq = lane >> 4;

    __shared__ __align__(16) char s_raw[2 * SLICE];
    char* slice = s_raw + sh * SLICE;
    _Float16* s_PM  = (_Float16*)(slice);                      // P / M (persistent)
    _Float16* s_vtw = (_Float16*)(slice + OFF_VT + sw * VTSZ); // own VT copy
    _Float16* s_gm  = (_Float16*)(slice + OFF_GM);
    int*      s_cnt = (int*)(slice + OFF_CNT);
    _Float16* s_d   = (_Float16*)(slice + OFF_VT);             // desc: VT region (dead after chain1)

    constexpr float LOG2E   = 1.44269504088896340736f;
    constexpr float TWO_PI  = 6.28318530717958647692f;
    constexpr float DLT     = TWO_PI / 16.0f;
    constexpr float INV_DLT = 16.0f / TWO_PI;
    constexpr float EPSF    = 1e-5f;

    const float st = sig_th[0];
    const float Kt = -LOG2E / (st * st + EPSF);
    const float sr = sig_rho[0];
    const float Kr = -LOG2E / (sr * sr + EPSF);
    float mr[NRH];
    #pragma unroll
    for (int r = 0; r < NRH; ++r) mr[r] = mu_rho[r * 16];

    // ---- zero P incl. pads (per-slice 425 int4, by that slice's 2 waves) ----
    #pragma unroll
    for (int x = 0; x < 4; ++x) {
        const int idx = x * 128 + sw * 64 + lane;
        if (idx < 425) ((int4*)s_PM)[idx] = make_int4(0, 0, 0, 0);
    }

    // ---- compaction: wave sw handles verts 64sw..64sw+63 of sample n ----
    const int v = sw * 64 + lane;
    const float  m   = mask_g[n * NVERT + v];
    const float  th0 = th_c[n * NVERT + v];
    const float  rho = rho_c[n * NVERT + v];
    const float4 f4  = *(const float4*)&feat_g[(n * NVERT + v) * 4];
    const bool act = (m != 0.0f);
    const unsigned long long bal = __ballot(act);
    if (lane == 0) s_cnt[sw] = (int)__popcll(bal);
    __syncthreads();                                        // [1] counts + P zero
    const int base = sw ? s_cnt[0] : 0;
    const int nc   = s_cnt[0] + s_cnt[1];
    if (act) {
        const int pos = base + (int)__popcll(bal & ((1ull << lane) - 1ull));
        int aa = (int)floorf(th0 * INV_DLT);
        aa = aa > 15 ? 15 : (aa < 0 ? 0 : aa);
        const float rvp = th0 - (float)aa * DLT - 0.5f * DLT;   // [-DLT/2, DLT/2)
        float R[NRH];
        #pragma unroll
        for (int r = 0; r < NRH; ++r) {
            const float dr = rho - mr[r];
            R[r] = m * exp2f(Kr * dr * dr);
        }
        const float fv[4] = {f4.x, f4.y, f4.z, f4.w};
        #pragma unroll
        for (int f = 0; f < 4; ++f) {
            #pragma unroll
            for (int r = 0; r < 4; ++r)
                s_PM[(f * 4 + r) * PSTR + pos] = (_Float16)(fv[f] * R[r]);
            s_PM[(16 + f) * PSTR + pos] = (_Float16)(fv[f] * R[4]);
        }
        #pragma unroll
        for (int r = 0; r < NRH; ++r)
            s_PM[(20 + r) * PSTR + pos] = (_Float16)R[r];
        s_PM[(pos >> 3) * PSTR + 128 + (pos & 7)] = (_Float16)(rvp * (2.0f * INV_DLT));
        ((char*)s_PM)[(16 + (pos >> 4)) * 2 * PSTR + 256 + (pos & 15)] = (char)aa;
        s_gm[pos] = (_Float16)exp2f(Kt * rvp * rvp);
    }
    __syncthreads();                                        // [2] P/gm/tails complete

    // ---- chain 1 (R16-verified): wave sw -> M tile sw, own VT copy ----
    f32x4 M[NDEG];
    #pragma unroll
    for (int ct = 0; ct < NDEG; ++ct) M[ct] = (f32x4){0.f, 0.f, 0.f, 0.f};
    const int arow = sw ? (16 + t) : t;
    const int nch = (nc + 31) >> 5;
    #pragma unroll 1
    for (int ch = 0; ch < nch; ++ch) {
        #pragma unroll
        for (int x = 0; x < 6; ++x)
            ((int4*)s_vtw)[x * 64 + lane] = make_int4(0, 0, 0, 0);
        {
            const int cl = lane >> 1;
            const int cg = ch * 32 + cl;
            if (cg < nc) {
                const float u = (float)s_PM[(cg >> 3) * PSTR + 128 + (cg & 7)];
                const float g = (float)s_gm[cg];
                const int   a = (int)((char*)s_PM)[(16 + (cg >> 4)) * 2 * PSTR + 256 + (cg & 15)];
                const int  dh = (lane & 1) * 3;
                float p0, p1, p2;
                if (dh == 0) { p0 = 1.0f; p1 = u; p2 = u * u; }
                else { const float u2 = u * u; p0 = u2 * u; p1 = u2 * u2; p2 = p0 * u2; }
                const int bi = (a * NDEG + dh) * VSTR + cl;
                s_vtw[bi]            = (_Float16)(g * p0);
                s_vtw[bi + VSTR]     = (_Float16)(g * p1);
                s_vtw[bi + 2 * VSTR] = (_Float16)(g * p2);
            }
        }
        const half8 a = *(const half8*)(s_PM + arow * PSTR + ch * 32 + kq * 8);
        #pragma unroll
        for (int ct = 0; ct < NDEG; ++ct) {
            const half8 b = *(const half8*)(s_vtw + (ct * 16 + t) * VSTR + kq * 8);
            M[ct] = __builtin_amdgcn_mfma_f32_16x16x32_f16(a, b, M[ct], 0, 0, 0);
        }
    }

    // ---- M -> LDS f16 A-layout. D: col=t, row=kq*4+reg ----
    #pragma unroll
    for (int ct = 0; ct < NDEG; ++ct) {
        const int md = ct * 16 + t;
        #pragma unroll
        for (int reg = 0; reg < 4; ++reg) {
            const int lr = kq * 4 + reg;
            if (sw == 0)
                s_PM[lr * PSTR + md] = (_Float16)M[ct][reg];
            else if (lr < 9)
                s_PM[(16 + lr) * PSTR + md] = (_Float16)M[ct][reg];
        }
    }
    __syncthreads();                                        // [3] M complete (VT now dead)

    // ---- chain2 A-frags -> regs (both tiles); desc goes to VT region, so
    //      no barrier needed between these reads and desc writes ----
    half8 A0[3], A1[3];
    #pragma unroll
    for (int ks = 0; ks < 3; ++ks) {
        A0[ks] = *(const half8*)(s_PM + t * PSTR + ks * 32 + kq * 8);
        A1[ks] = *(const half8*)(s_PM + (16 + t) * PSTR + ks * 32 + kq * 8);
    }

    // ---- chain 2: wave sw -> nt-groups 2sw, 2sw+1; fused epilogue ----
    const half8* wsv = (const half8*)ws;
    #pragma unroll 1
    for (int gg = 0; gg < 2; ++gg) {
        const int g = sw * 2 + gg;
        f32x4 C0g[4], C1g[4];
        #pragma unroll
        for (int j = 0; j < 4; ++j) {
            C0g[j] = (f32x4){0.f, 0.f, 0.f, 0.f};
            C1g[j] = (f32x4){0.f, 0.f, 0.f, 0.f};
        }
        #pragma unroll
        for (int j = 0; j < 4; ++j) {
            const int nt = g * 4 + j;
            half8 b0, b1, b2;
            if (USEWS) {
                b0 = wsv[(size_t)((nt * 3 + 0) * 64 + lane)];
                b1 = wsv[(size_t)((nt * 3 + 1) * 64 + lane)];
                b2 = wsv[(size_t)((nt * 3 + 2) * 64 + lane)];
            } else {
                #pragma unroll
                for (int ks = 0; ks < 3; ++ks) {
                    half8 bb;
                    #pragma unroll
                    for (int jj = 0; jj < 8; ++jj) {
                        const int k = ks * 32 + kq * 8 + jj;
                        const int a = k / NDEG, d = k % NDEG;
                        const int mm = ((a + nt) & 15) - t;
                        const float s = fmaf((float)mm, DLT, 0.5f * DLT);
                        const float z = 2.0f * 0.69314718055994530942f * Kt * s * (0.5f * DLT);
                        float val = exp2f(Kt * s * s);
                        for (int dd = 1; dd <= d; ++dd) val *= z / (float)dd;
                        bb[jj] = (_Float16)val;
                    }
                    if (ks == 0) b0 = bb; else if (ks == 1) b1 = bb; else b2 = bb;
                }
            }
            C0g[j] = __builtin_amdgcn_mfma_f32_16x16x32_f16(A0[0], b0, C0g[j], 0, 0, 0);
            C1g[j] = __builtin_amdgcn_mfma_f32_16x16x32_f16(A1[0], b0, C1g[j], 0, 0, 0);
            C0g[j] = __builtin_amdgcn_mfma_f32_16x16x32_f16(A0[1], b1, C0g[j], 0, 0, 0);
            C1g[j] = __builtin_amdgcn_mfma_f32_16x16x32_f16(A1[1], b1, C1g[j], 0, 0, 0);
            C0g[j] = __builtin_amdgcn_mfma_f32_16x16x32_f16(A0[2], b2, C0g[j], 0, 0, 0);
            C1g[j] = __builtin_amdgcn_mfma_f32_16x16x32_f16(A1[2], b2, C1g[j], 0, 0, 0);
        }
        // fused epilogue (R5-verified): desc = num/(den+eps) -> s_d[i][k][bb]
        #pragma unroll
        for (int j = 0; j < 4; ++j) {
            const int nt = g * 4 + j;
            float den[5], inv[5];
            #pragma unroll
            for (int r = 0; r < 4; ++r) den[r] = __shfl(C1g[j][r], 16 + t);
            den[4] = __shfl(C1g[j][0], 32 + t);
            #pragma unroll
            for (int r = 0; r < NRH; ++r) {
                const float x = den[r] + EPSF;
                float vv = __builtin_amdgcn_rcpf(x);
                inv[r] = vv * (2.0f - x * vv);
            }
            #pragma unroll
            for (int reg = 0; reg < 4; ++reg)
                s_d[kq * 1280 + nt * DSTR + reg * 16 + t] =
                    (_Float16)(C0g[j][reg] * inv[reg]);
            if (kq == 0) {
                #pragma unroll
                for (int reg = 0; reg < 4; ++reg)
                    s_d[reg * 1280 + nt * DSTR + 64 + t] =
                        (_Float16)(C1g[j][reg] * inv[4]);
            }
        }
    }
    __syncthreads();                                        // [4] desc complete

    // ---- phase 2: wave sw -> features 2sw, 2sw+1 ----
    #pragma unroll 1
    for (int ii = 0; ii < 2; ++ii) {
        const int i = sw * 2 + ii;
        f32x4 Cc[5];
        #pragma unroll
        for (int tl = 0; tl < 5; ++tl) Cc[tl] = (f32x4){0.f, 0.f, 0.f, 0.f};
        #pragma unroll
        for (int ks = 0; ks < 3; ++ks) {
            const half8 a = *(const half8*)(s_d + i * 1280 + t * DSTR + ks * 32 + kq * 8);
            #pragma unroll
            for (int tl = 0; tl < 5; ++tl) {
                half8 b;
                if (USEWS) {
                    b = wsv[(size_t)((NSET_C + (i * 5 + tl) * 3 + ks) * 64 + lane)];
                } else {
                    const int cc  = tl * 16 + t;
                    const int bb0 = ks * 32 + kq * 8;
                    #pragma unroll
                    for (int j = 0; j < 8; ++j) {
                        const int bb = bb0 + j;
                        b[j] = (_Float16)((bb < NBINS) ? Wc[i * NBINS * NBINS + bb * NBINS + cc] : 0.0f);
                    }
                }
                Cc[tl] = __builtin_amdgcn_mfma_f32_16x16x32_f16(a, b, Cc[tl], 0, 0, 0);
            }
        }
        #pragma unroll
        for (int tl = 0; tl < 5; ++tl) {
            float mx = fmaxf(fmaxf(Cc[tl][0], Cc[tl][1]), fmaxf(Cc[tl][2], Cc[tl][3]));
            mx = fmaxf(mx, __shfl_xor(mx, 16));
            mx = fmaxf(mx, __shfl_xor(mx, 32));
            if (lane < 16) {
                const int cc = tl * 16 + lane;
                out[(size_t)n * 320 + i * NBINS + cc] =
                    fmaxf(mx + bcv[i * NBINS + cc], 0.0f);
            }
        }
    }
}

extern "C" void kernel_launch(void* const* d_in, const int* in_sizes, int n_in,
                              void* d_out, int out_size, void* d_ws, size_t ws_size,
                              hipStream_t stream) {
    const float* rho   = (const float*)d_in[0];
    const float* theta = (const float*)d_in[1];
    const float* feat  = (const float*)d_in[2];
    const float* mask  = (const float*)d_in[3];
    const float* mu_r  = (const float*)d_in[4];
    const float* sg_r  = (const float*)d_in[5];
    const float* mu_t  = (const float*)d_in[6];
    const float* sg_t  = (const float*)d_in[7];
    const float* W     = (const float*)d_in[8];
    const float* bconv = (const float*)d_in[9];
    float* outp = (float*)d_out;

    const int nsamp = in_sizes[0] / NVERT;
    const int useWs = (ws_size >= (size_t)WS_BYTES) ? 1 : 0;
    _Float16* wsh = (_Float16*)d_ws;
    const int nblk = (nsamp + 1) / 2;

    if (useWs) {
        prep_frags<<<NSET_C + NSET_W, 64, 0, stream>>>(W, sg_t, wsh);
        masif_geo_conv<1><<<nblk, 256, 0, stream>>>(
            rho, theta, feat, mask, mu_r, sg_r, mu_t, sg_t, W, bconv,
            wsh, nsamp, outp);
    } else {
        masif_geo_conv<0><<<nblk, 256, 0, stream>>>(
            rho, theta, feat, mask, mu_r, sg_r, mu_t, sg_t, W, bconv,
            wsh, nsamp, outp);
    }
}